// Round 5
// baseline (312.789 us; speedup 1.0000x reference)
//
#include <hip/hip_runtime.h>

// JointNet: out[n,t,u,v] = tanh(enc_proj[t,n,:] + pred_proj[u,n,:] + b1) . W2^T + b2
// T=200 U=50 N=8  ENC=PRED=512  H=640  V=1000
// m = ((n*200+t)*50+u) -> flat row-major [80000][1000] GEMM with A generated on the fly.
// Round-5 structure: per-WG 64 m-rows; full-K hidden tile resident in LDS (tanh once);
// barrier-free main loop; B (W2b) global->reg with half-step prefetch.

typedef __attribute__((ext_vector_type(4))) float f32x4;
typedef __attribute__((ext_vector_type(8))) short s16x8;

#define HDIM 640
#define VOCAB 1000

__device__ __forceinline__ float tanh_fast(float x) {
  float e = __expf(2.0f * x);
  return 1.0f - 2.0f * __builtin_amdgcn_rcpf(e + 1.0f);
}

__device__ __forceinline__ unsigned short f2bf(float f) {
  unsigned int u = __float_as_uint(f);
  return (unsigned short)((u + 0x7FFFu + ((u >> 16) & 1u)) >> 16);  // RNE
}

// ---- K0: W2 f32 [1000][640] -> bf16 [1024][640], rows 1000..1023 zero ----
__global__ void k_prep(const float* __restrict__ W2, unsigned short* __restrict__ W2b) {
  int i = blockIdx.x * 256 + threadIdx.x;  // 81920 = 1024*640/8
  int v = i / 80;
  int kc = (i - v * 80) * 8;
  s16x8 o = {0, 0, 0, 0, 0, 0, 0, 0};
  if (v < VOCAB) {
    const float* src = W2 + v * HDIM + kc;
    f32x4 a = *(const f32x4*)src;
    f32x4 b = *(const f32x4*)(src + 4);
#pragma unroll
    for (int j = 0; j < 4; ++j) {
      o[j] = (short)f2bf(a[j]);
      o[j + 4] = (short)f2bf(b[j]);
    }
  }
  *(s16x8*)(W2b + (size_t)v * HDIM + kc) = o;
}

// ---- K1: projections, f32 tiled GEMM ----
__global__ __launch_bounds__(256) void k_proj(const float* __restrict__ enc,
                                              const float* __restrict__ pred,
                                              const float* __restrict__ W1,
                                              const float* __restrict__ b1,
                                              float* __restrict__ EPPB) {
  __shared__ float As[16][68];
  __shared__ float Bs[16][68];
  const int tid = threadIdx.x;
  const int tx = tid & 15, ty = tid >> 4;
  const int h0 = blockIdx.x * 64;
  const int m0 = blockIdx.y * 64;
  const bool isPred = (m0 >= 1600);
  const float* A = isPred ? pred : enc;
  const int arow0 = isPred ? (m0 - 1600) : m0;
  const int armax = isPred ? 399 : 1599;
  const int koff = isPred ? 512 : 0;
  float acc[4][4] = {};
  for (int k0 = 0; k0 < 512; k0 += 16) {
#pragma unroll
    for (int q = 0; q < 4; ++q) {
      int r = ty + q * 16;
      int ar = arow0 + r;
      if (ar > armax) ar = armax;
      As[tx][r] = A[ar * 512 + k0 + tx];
      Bs[tx][r] = W1[(h0 + r) * 1024 + koff + k0 + tx];
    }
    __syncthreads();
#pragma unroll
    for (int kk = 0; kk < 16; ++kk) {
      f32x4 a = *(const f32x4*)&As[kk][ty * 4];
      f32x4 b = *(const f32x4*)&Bs[kk][tx * 4];
#pragma unroll
      for (int i = 0; i < 4; ++i)
#pragma unroll
        for (int j = 0; j < 4; ++j) acc[i][j] += a[i] * b[j];
    }
    __syncthreads();
  }
#pragma unroll
  for (int i = 0; i < 4; ++i) {
    int m = m0 + ty * 4 + i;
    if (m < 2000) {
#pragma unroll
      for (int j = 0; j < 4; ++j) {
        int h = h0 + tx * 4 + j;
        float val = acc[i][j];
        if (m >= 1600) val += b1[h];
        EPPB[m * HDIM + h] = val;
      }
    }
  }
}

// ---- K2: fused joint GEMM, 64m rows/WG, full-K A in LDS, barrier-free loop ----
__global__ __launch_bounds__(256, 2) void k_joint(const float* __restrict__ EPPB,
                                                  const unsigned short* __restrict__ W2b,
                                                  const float* __restrict__ b2,
                                                  float* __restrict__ out) {
  extern __shared__ char Asm[];  // 64 rows x 1280 B (full K), XOR-swizzled: 81920 B

  // bijective XCD-chunked swizzle over 1250 WGs (1250 = 8*156 + 2)
  const int bid = blockIdx.x;
  const int xcd = bid & 7, seq = bid >> 3;
  const int swz = (xcd < 2 ? xcd * 157 : 314 + (xcd - 2) * 156) + seq;
  const int m0 = swz * 64;

  const int tid = threadIdx.x;

  // ---- phase 0: hidden = tanh(ep + pb) -> bf16 LDS, full K, once ----
  {
    const int row = tid >> 2;          // 64 rows, 4 threads/row
    const int kq4 = (tid & 3) * 160;   // 160 elems each
    const int m = m0 + row;
    const int n = m / 10000;
    const int rr = m - n * 10000;
    const int t = rr / 50;
    const int u = rr - t * 50;
    const float* ep = EPPB + (t * 8 + n) * HDIM + kq4;
    const float* pb = EPPB + (1600 + u * 8 + n) * HDIM + kq4;
    const int rowbase = row * 1280;
    const int rsw = (row & 7) << 4;
#pragma unroll 4
    for (int j = 0; j < 20; ++j) {
      const int k = j * 8;
      f32x4 e0 = *(const f32x4*)(ep + k);
      f32x4 e1 = *(const f32x4*)(ep + k + 4);
      f32x4 p0 = *(const f32x4*)(pb + k);
      f32x4 p1 = *(const f32x4*)(pb + k + 4);
      s16x8 h;
#pragma unroll
      for (int i = 0; i < 4; ++i) {
        h[i] = (short)f2bf(tanh_fast(e0[i] + p0[i]));
        h[i + 4] = (short)f2bf(tanh_fast(e1[i] + p1[i]));
      }
      *(s16x8*)(Asm + rowbase + (((kq4 + k) * 2) ^ rsw));
      *(s16x8*)(Asm + rowbase + (((kq4 + k) * 2) ^ rsw)) = h;
    }
  }
  __syncthreads();  // the only barrier

  const int wid = tid >> 6;          // 4 waves = 4 v-slices of 128
  const int lane = tid & 63;
  const int lr = lane & 15;
  const int kq = lane >> 4;
  const int sw = (lr & 7) << 4;
  const int vwave = wid * 128;

  const char* const w2bytes = (const char*)W2b;

  for (int vp = 0; vp < 2; ++vp) {
    const int vbase = vp * 512 + vwave;
    const char* wrow = w2bytes + (size_t)(vbase + lr) * 1280 + kq * 16;

    f32x4 acc[4][8];
    const f32x4 zero = {0.0f, 0.0f, 0.0f, 0.0f};
#pragma unroll
    for (int mi = 0; mi < 4; ++mi)
#pragma unroll
      for (int ni = 0; ni < 8; ++ni) acc[mi][ni] = zero;

    s16x8 bA[8], bB[8];
    // preload (ks=0, kk=0)
#pragma unroll
    for (int ni = 0; ni < 8; ++ni)
      bA[ni] = *(const s16x8*)(wrow + ni * 16 * 1280);

#pragma unroll 1
    for (int ks = 0; ks < 10; ++ks) {
      // half kk=0: read A frags, prefetch bB=(ks,1), MFMA bA
      s16x8 aA[4];
      {
        const int kt = (ks * 128 + kq * 16) ^ sw;
#pragma unroll
        for (int mi = 0; mi < 4; ++mi)
          aA[mi] = *(const s16x8*)(Asm + (mi * 16 + lr) * 1280 + kt);
      }
#pragma unroll
      for (int ni = 0; ni < 8; ++ni)
        bB[ni] = *(const s16x8*)(wrow + ks * 128 + 64 + ni * 16 * 1280);
      __builtin_amdgcn_s_setprio(1);
#pragma unroll
      for (int mi = 0; mi < 4; ++mi)
#pragma unroll
        for (int ni = 0; ni < 8; ++ni)
          acc[mi][ni] = __builtin_amdgcn_mfma_f32_16x16x32_bf16(bA[ni], aA[mi], acc[mi][ni], 0, 0, 0);
      __builtin_amdgcn_s_setprio(0);

      // half kk=1: read A frags, prefetch bA=(ks+1,0), MFMA bB
      s16x8 aB[4];
      {
        const int kt = (ks * 128 + 64 + kq * 16) ^ sw;
#pragma unroll
        for (int mi = 0; mi < 4; ++mi)
          aB[mi] = *(const s16x8*)(Asm + (mi * 16 + lr) * 1280 + kt);
      }
      if (ks < 9) {
#pragma unroll
        for (int ni = 0; ni < 8; ++ni)
          bA[ni] = *(const s16x8*)(wrow + (ks + 1) * 128 + ni * 16 * 1280);
      }
      __builtin_amdgcn_s_setprio(1);
#pragma unroll
      for (int mi = 0; mi < 4; ++mi)
#pragma unroll
        for (int ni = 0; ni < 8; ++ni)
          acc[mi][ni] = __builtin_amdgcn_mfma_f32_16x16x32_bf16(bB[ni], aB[mi], acc[mi][ni], 0, 0, 0);
      __builtin_amdgcn_s_setprio(0);
    }

    // store this v-pass: lane holds 4 consecutive v per acc reg
#pragma unroll
    for (int ni = 0; ni < 8; ++ni) {
      int vq = vbase + ni * 16 + kq * 4;
      if (vq < VOCAB) {
        f32x4 bv = *(const f32x4*)(b2 + vq);
#pragma unroll
        for (int mi = 0; mi < 4; ++mi) {
          int m = m0 + mi * 16 + lr;
          f32x4 r = acc[mi][ni] + bv;
          *(f32x4*)(out + (size_t)m * VOCAB + vq) = r;
        }
      }
    }
  }
}

extern "C" void kernel_launch(void* const* d_in, const int* in_sizes, int n_in,
                              void* d_out, int out_size, void* d_ws, size_t ws_size,
                              hipStream_t stream) {
  const float* enc = (const float*)d_in[0];
  const float* pred = (const float*)d_in[1];
  const float* W1 = (const float*)d_in[2];
  const float* b1 = (const float*)d_in[3];
  const float* W2 = (const float*)d_in[4];
  const float* b2 = (const float*)d_in[5];
  float* out = (float*)d_out;

  unsigned short* W2b = (unsigned short*)d_ws;    // 1,310,720 B
  float* EPPB = (float*)((char*)d_ws + 1310720);  // 5,120,000 B

  hipFuncSetAttribute((const void*)k_joint, hipFuncAttributeMaxDynamicSharedMemorySize, 81920);

  k_prep<<<320, 256, 0, stream>>>(W2, W2b);
  k_proj<<<dim3(10, 32), 256, 0, stream>>>(enc, pred, W1, b1, EPPB);
  k_joint<<<1250, 256, 81920, stream>>>(EPPB, W2b, b2, out);
}